// Round 10
// baseline (268.073 us; speedup 1.0000x reference)
//
#include <hip/hip_runtime.h>

// out = X · M,  M = (W^T W)/32 (symmetric 1024x1024)
// X: 65536x1024 fp32.  W: 1024x1024 fp32.  out: 65536x1024 fp32.
// K1: compute_M (proven VALU outer-product, 256 blocks)
// K2: gemm1p — 256x256 tile, BK=32, 8 waves (2Mx4N, wave tile 128x64),
//   ONE barrier per K-tile. 4-slot ring per operand (128 KB LDS).
//   A: fp32 asm loads (lookahead 3) -> cvt -> swizzled ds_write (lookahead 2)
//   B: global_load_lds, pre-swizzled source (lookahead 2)
// [R10 fix of R9's 1e24 fail: prologue issue order was ...B0,B1,A2 so iter-0's
//  top VMC(2) left A2's newest 2 loads unlanded -> cvt8 of garbage regs.
//  Reordered to A0,A1,B0,A2,B1 so VMC(6) leaves [A2(4),B1(2)] — identical to
//  the steady-state queue [A(j+2),B(j+1)]. No other change.]
// Ledger (verified by induction):
//  top of iter j:  outstanding [A(j+2)4, B(j+1)2] -> VMC(2) forces A(j+2)
//  end of iter j:  outstanding [B(j+1)2, A(j+3)4, B(j+2)2] -> VMC(6) forces
//                  B(j+1) BEFORE the closing BAR (cross-wave-safe publish).
//  tail: j=29 end VMC(2) (forces B30); j=30 end VMC(0) (forces B31).
//  Slot ring: iter j reads slot j&3, writes slot (j+2)&3; one barrier per
//  iter keeps all waves in the same iteration body -> no read∩write slot.
//  A ds_writes drained by LGKM0 before closing BAR; read 2 barriers later.

typedef unsigned short u16;
typedef unsigned int u32;
typedef __bf16 bf16x8 __attribute__((ext_vector_type(8)));
typedef float f32x4 __attribute__((ext_vector_type(4)));

#define BAR() __builtin_amdgcn_s_barrier()
#define LGKM0() asm volatile("s_waitcnt lgkmcnt(0)" ::: "memory")
#define VMC(n) asm volatile("s_waitcnt vmcnt(" #n ")" ::: "memory")
#define SCHED0() __builtin_amdgcn_sched_barrier(0)

__device__ __forceinline__ u16 f2bf(float f) {  // RNE fp32->bf16
  u32 u = __float_as_uint(f);
  u += 0x7fffu + ((u >> 16) & 1u);
  return (u16)(u >> 16);
}

__device__ __forceinline__ void gload_lds16(const void* g, void* l) {
  __builtin_amdgcn_global_load_lds((const __attribute__((address_space(1))) u32*)g,
                                   (__attribute__((address_space(3))) u32*)l,
                                   16, 0, 0);
}

__device__ __forceinline__ void load2x16(const float* p, f32x4& a, f32x4& b) {
  asm volatile("global_load_dwordx4 %0, %2, off\n\t"
               "global_load_dwordx4 %1, %2, off offset:16"
               : "=&v"(a), "=&v"(b)
               : "v"(p)
               : "memory");
}

__device__ __forceinline__ bf16x8 cvt8(f32x4 a, f32x4 b) {
  bf16x8 h;
  h[0] = (__bf16)a[0]; h[1] = (__bf16)a[1]; h[2] = (__bf16)a[2]; h[3] = (__bf16)a[3];
  h[4] = (__bf16)b[0]; h[5] = (__bf16)b[1]; h[6] = (__bf16)b[2]; h[7] = (__bf16)b[3];
  return h;
}

// ---------------- K1: M = (W^T W)/32, 64x64 tile per block --------------------
__global__ __launch_bounds__(256) void compute_M(const float* __restrict__ W,
                                                 u16* __restrict__ Mb) {
  __shared__ float w1[32][64];
  __shared__ float w2[32][64];
  const int t = threadIdx.x;
  const int i0 = blockIdx.y * 64;
  const int j0 = blockIdx.x * 64;
  const int tx = t & 15, ty = t >> 4;
  float acc[4][4] = {};
  for (int u0 = 0; u0 < 1024; u0 += 32) {
    __syncthreads();
#pragma unroll
    for (int p = 0; p < 2; ++p) {
      int idx = p * 256 + t;
      int lu = idx >> 4, lc = (idx & 15) * 4;
      *(float4*)&w1[lu][lc] = *(const float4*)(W + (size_t)(u0 + lu) * 1024 + i0 + lc);
      *(float4*)&w2[lu][lc] = *(const float4*)(W + (size_t)(u0 + lu) * 1024 + j0 + lc);
    }
    __syncthreads();
#pragma unroll 8
    for (int u = 0; u < 32; ++u) {
      float4 a = *(const float4*)&w1[u][ty * 4];
      float4 b = *(const float4*)&w2[u][tx * 4];
      float av[4] = {a.x, a.y, a.z, a.w};
      float bv[4] = {b.x, b.y, b.z, b.w};
#pragma unroll
      for (int e = 0; e < 4; ++e)
#pragma unroll
        for (int f = 0; f < 4; ++f)
          acc[e][f] += av[e] * bv[f];
    }
  }
  const float s = 0.03125f;
#pragma unroll
  for (int e = 0; e < 4; ++e) {
    ushort4 v;
    v.x = f2bf(acc[e][0] * s);
    v.y = f2bf(acc[e][1] * s);
    v.z = f2bf(acc[e][2] * s);
    v.w = f2bf(acc[e][3] * s);
    *(ushort4*)(Mb + (size_t)(i0 + ty * 4 + e) * 1024 + j0 + tx * 4) = v;
  }
}

// ---------------- K2: one-barrier-per-K-tile fused-cvt GEMM -------------------
__global__ __launch_bounds__(512, 2) void gemm1p(const float* __restrict__ X,
                                                 const u16* __restrict__ Mb,
                                                 float* __restrict__ out) {
  __shared__ u16 lA[4][8192];  // 4 slots x 256 rows x 32 bf16 = 64 KB
  __shared__ u16 lB[4][8192];  // 64 KB

  const int p = blockIdx.x;                  // nwg = 1024 (%8==0)
  const int wg = (p & 7) * 128 + (p >> 3);   // chunked XCD swizzle
  const int bm = wg >> 2;                    // 0..255
  const int bn = wg & 3;                     // 0..3 (A-panel shared by 4 on XCD)
  const size_t r0 = (size_t)bm * 256;
  const int c0 = bn * 256;

  const int t = threadIdx.x;
  const int lane = t & 63;
  const int w = t >> 6;
  const int wr = w >> 2, wc = w & 3;         // 2x4 wave grid, wave tile 128x64
  const int fr = lane & 15;
  const int kc = lane >> 4;

  const int srow = t >> 2;                   // 0..127
  const int scl = t & 3;
  const int csw = scl ^ ((srow >> 1) & 3);   // XOR chunk swizzle (involution)
  const float* aL = X + (r0 + srow) * 1024 + scl * 8;
  const float* aH = X + (r0 + 128 + srow) * 1024 + scl * 8;
  const u16* gB = Mb + (size_t)(c0 + srow) * 1024 + csw * 8;        // pre-swz src
  const u16* gB2 = Mb + (size_t)(c0 + 128 + srow) * 1024 + csw * 8;
  u16* wLp = &lA[0][srow * 32 + csw * 8];    // swizzled A write (slot 0 base)
  u16* wHp = wLp + 128 * 32;
  u16* bDst = &lB[0][w * 512];               // linear B dest (slot 0 base)

  f32x4 acc[8][4] = {};
  f32x4 pfa, pfb, pfc, pfd;                  // pending A (kt j+2 at iter-j top)
  f32x4 q0a, q0b, q0c, q0d, q1a, q1b, q1c, q1d;

  // ---- prologue (issue order MUST be A0,A1,B0,A2,B1 — see header note) ----
  load2x16(aL + 0, q0a, q0b);   load2x16(aH + 0, q0c, q0d);     // A kt0 (4)
  load2x16(aL + 32, q1a, q1b);  load2x16(aH + 32, q1c, q1d);    // A kt1 (4)
  gload_lds16(gB + 0, bDst);                                     // B kt0 -> slot0
  gload_lds16(gB2 + 0, bDst + 4096);
  load2x16(aL + 64, pfa, pfb);  load2x16(aH + 64, pfc, pfd);    // A kt2 -> pend
  gload_lds16(gB + 32, bDst + 8192);                             // B kt1 -> slot1
  gload_lds16(gB2 + 32, bDst + 8192 + 4096);
  VMC(6);   // forces A0,A1,B0; leaves [A2(4), B1(2)] = steady-state order
  SCHED0();
  *(bf16x8*)(wLp + 0 * 8192) = cvt8(q0a, q0b);                   // A kt0 -> slot0
  *(bf16x8*)(wHp + 0 * 8192) = cvt8(q0c, q0d);
  *(bf16x8*)(wLp + 1 * 8192) = cvt8(q1a, q1b);                   // A kt1 -> slot1
  *(bf16x8*)(wHp + 1 * 8192) = cvt8(q1c, q1d);
  LGKM0(); SCHED0();
  BAR();

  for (int j = 0; j < 32; ++j) {
    const u16* bA = &lA[j & 3][0];
    const u16* bB = &lB[j & 3][0];
    const int sb = (j + 2) & 3;

    VMC(2);   // forces A(j+2) quad (per-wave cvt dep); leaves B(j+1)
    SCHED0();
    if (j <= 29) {  // cvt A kt j+2 -> slot sb
      *(bf16x8*)(wLp + sb * 8192) = cvt8(pfa, pfb);
      *(bf16x8*)(wHp + sb * 8192) = cvt8(pfc, pfd);
    }
    // fragment reads (compiler inserts counted lgkm waits before MFMAs)
    bf16x8 bf[4], af[8];
#pragma unroll
    for (int n = 0; n < 4; ++n) {
      const int row = wc * 64 + n * 16 + fr;
      const int cs = kc ^ ((row >> 1) & 3);
      bf[n] = *(const bf16x8*)&bB[row * 32 + cs * 8];
    }
#pragma unroll
    for (int m = 0; m < 8; ++m) {
      const int row = wr * 128 + m * 16 + fr;
      const int cs = kc ^ ((row >> 1) & 3);
      af[m] = *(const bf16x8*)&bA[row * 32 + cs * 8];
    }
    if (j <= 28) {  // issue A kt j+3 (asm, enters vmcnt queue before B)
      load2x16(aL + (j + 3) * 32, pfa, pfb);
      load2x16(aH + (j + 3) * 32, pfc, pfd);
    }
    if (j <= 29) {  // stage B kt j+2 -> slot sb
      gload_lds16(gB + (j + 2) * 32, (void*)(bDst + sb * 8192));
      gload_lds16(gB2 + (j + 2) * 32, (void*)(bDst + sb * 8192 + 4096));
    }
    __builtin_amdgcn_s_setprio(1);
#pragma unroll
    for (int m = 0; m < 8; ++m)
#pragma unroll
      for (int n = 0; n < 4; ++n)
        acc[m][n] = __builtin_amdgcn_mfma_f32_16x16x32_bf16(af[m], bf[n],
                                                            acc[m][n], 0, 0, 0);
    __builtin_amdgcn_s_setprio(0);
    // end: cross-wave guarantees BEFORE the closing barrier
    if (j <= 28) {
      VMC(6);   // forces B(j+1)
    } else if (j == 29) {
      VMC(2);   // forces B30
    } else if (j == 30) {
      VMC(0);   // forces B31
    }
    LGKM0();    // drains this wave's A ds_writes (slot sb, read at iter j+2)
    SCHED0();
    BAR();
  }

  // ---- epilogue: C layout col=lane&15, row=(lane>>4)*4+reg ----
  const int ocol = lane & 15;
  const int orow = (lane >> 4) * 4;
#pragma unroll
  for (int m = 0; m < 8; ++m) {
    const size_t rbase = (r0 + wr * 128 + m * 16 + orow) * 1024;
#pragma unroll
    for (int n = 0; n < 4; ++n) {
      float* o = out + rbase + (c0 + wc * 64 + n * 16 + ocol);
      o[0] = acc[m][n][0];
      o[1024] = acc[m][n][1];
      o[2048] = acc[m][n][2];
      o[3072] = acc[m][n][3];
    }
  }
}

extern "C" void kernel_launch(void* const* d_in, const int* in_sizes, int n_in,
                              void* d_out, int out_size, void* d_ws, size_t ws_size,
                              hipStream_t stream) {
  const float* X = (const float*)d_in[0];
  const float* W = (const float*)d_in[1];
  float* out = (float*)d_out;
  u16* Mb = (u16*)d_ws;  // 2 MB scratch

  compute_M<<<dim3(16, 16), 256, 0, stream>>>(W, Mb);
  gemm1p<<<1024, 512, 0, stream>>>(X, Mb, out);
}